// Round 6
// baseline (6074.802 us; speedup 1.0000x reference)
//
#include <hip/hip_runtime.h>
#include <math.h>

// CustomRNN: B=64,S=512,I=256,H=512,O=256,L=2 (fp32)
// R6 = R3 (last-known-good dataflow, bit-identical arithmetic) + ONE change:
// weight slices pinned in VGPRs via empty asm (R3's measured deficiency was
// VGPR_Count=96 -> weights re-streamed from L2 every tick).
//   fold:  W0 = Win@Wi0, b0 = bin@Wi0 + bi0 + bh0
//   rnn:   persistent 256 WGs (1/CU). L0 WGs: h0(t)=tanh(h0(t-1)@Wh0 + x_t@W0 + b0)
//          L1 WGs: h1(t)=tanh(h0(t)@Wi1 + h1(t-1)@Wh1 + b1)
//   out_k: out = H1 @ W_out + b_out ; tail_k: final hidden states.
// Invariant restored from R3: every line written during rnn is ONLY read via
// sc1 (MALL-coherent) loads inside rnn — no normal-load of sc1-written or
// later-overwritten data => no stale-L2-copy hazard (R4's zval bug class).
// Sync: R3's per-(layer,rg) fetch_add counters, quorum 16, depth-4 h0 ring.

constexpr int BB = 64;
constexpr int SS = 512;
constexpr int II = 256;
constexpr int HH = 512;
constexpr int OO = 256;
constexpr int BH = BB * HH;       // 32768
constexpr int RING_D = 4;
constexpr int STR0 = 772;         // 768 + 4 pad (L0: 512 h + 256 x)
constexpr int STR1 = 1028;        // 1024 + 4 pad (L1: 512 h0 + 512 h1)
constexpr int PSTR = 36;          // partial-slot stride (16B-aligned, bank-spread)
constexpr int HREG = 8 * STR1;    // 8224 floats
constexpr int PREG = 8 * 32 * PSTR; // 9216 floats
constexpr int LDS_BYTES = (HREG + PREG) * 4;  // 69760 B

#define SCOPE_AGENT __HIP_MEMORY_SCOPE_AGENT

__device__ __forceinline__ unsigned ld_flag(const unsigned* p) {
    return __hip_atomic_load((unsigned*)p, __ATOMIC_RELAXED, SCOPE_AGENT);
}
__device__ __forceinline__ void add_flag(unsigned* p) {
    __hip_atomic_fetch_add(p, 1u, __ATOMIC_RELAXED, SCOPE_AGENT);
}
__device__ __forceinline__ void wait_ge(const unsigned* p, unsigned target) {
    while (ld_flag(p) < target) __builtin_amdgcn_s_sleep(1);
}

union F2U { float2 f; unsigned long long u; };
__device__ __forceinline__ float2 ld_coh2(const float* p) {
    F2U v;
    v.u = __hip_atomic_load((unsigned long long*)p, __ATOMIC_RELAXED, SCOPE_AGENT);
    return v.f;
}
__device__ __forceinline__ void st_coh1(float* p, float a) {
    __hip_atomic_store(p, a, __ATOMIC_RELAXED, SCOPE_AGENT);
}

template <int N>
__device__ __forceinline__ void pin4(float4 (&w)[N]) {
    #pragma unroll
    for (int i = 0; i < N; ++i)
        asm volatile("" : "+v"(w[i].x), "+v"(w[i].y), "+v"(w[i].z), "+v"(w[i].w));
}

// ---------------- fold: W0 = Win@Wi0, b0 = bin@Wi0 + bi0 + bh0 ----------------
__global__ __launch_bounds__(256) void fold_k(
    const float* __restrict__ Win, const float* __restrict__ bin,
    const float* __restrict__ Wi2h, const float* __restrict__ bi2h,
    const float* __restrict__ bh2h,
    float* __restrict__ W0, float* __restrict__ b0)
{
    int gid = blockIdx.x * 256 + threadIdx.x;
    const float* Wi0 = Wi2h;
    if (gid < II * HH) {
        int i = gid / HH, j = gid % HH;
        float acc = 0.f;
        for (int k = 0; k < HH; ++k)
            acc = fmaf(Win[i * HH + k], Wi0[k * HH + j], acc);
        W0[gid] = acc;
    } else if (gid < II * HH + HH) {
        int j = gid - II * HH;
        float acc = bi2h[j] + bh2h[j];
        for (int k = 0; k < HH; ++k)
            acc = fmaf(bin[k], Wi0[k * HH + j], acc);
        b0[j] = acc;
    }
}

// ---------------- persistent sequential kernel ----------------
template <int LAYER>
__device__ __forceinline__ void rnn_body(
    const float* __restrict__ x, const float* __restrict__ hprev,
    const float* __restrict__ Wi2h, const float* __restrict__ bi2h,
    const float* __restrict__ Wh2h, const float* __restrict__ bh2h,
    const float* __restrict__ W0, const float* __restrict__ b0,
    float* __restrict__ ring, float* __restrict__ H1,
    unsigned* __restrict__ c0, unsigned* __restrict__ c1,
    float* hbuf, float* pbuf)
{
    constexpr int NJ  = LAYER ? 8 : 6;           // k-range = NJ*128
    constexpr int STR = LAYER ? STR1 : STR0;

    const int tid  = threadIdx.x;
    const int id   = blockIdx.x & 127;
    const int rg   = id >> 4;        // 0..7  (8 rows each)
    const int cg   = id & 15;        // 0..15 (32 cols each)
    const int row0 = rg * 8;
    const int col0 = cg * 32;
    const int kg   = tid & 31;
    const int cgrp = (tid >> 5) & 7;
    const int cbase = col0 + cgrp * 4;

    // ---- weight slice -> registers, pinned for all 512 ticks ----
    float4 w4[NJ * 4];
    #pragma unroll
    for (int j = 0; j < NJ; ++j) {
        #pragma unroll
        for (int e = 0; e < 4; ++e) {
            int k = j * 128 + kg * 4 + e;
            const float* src;
            if (LAYER == 0)
                src = (k < 512) ? (Wh2h + (size_t)k * HH + cbase)
                                : (W0 + (size_t)(k - 512) * HH + cbase);
            else
                src = (k < 512) ? (Wi2h + (size_t)HH * HH + (size_t)k * HH + cbase)
                                : (Wh2h + (size_t)HH * HH + (size_t)(k - 512) * HH + cbase);
            w4[j * 4 + e] = *(const float4*)src;
        }
    }
    pin4(w4);

    float bias_red;
    {
        int c = col0 + (tid & 31);
        bias_red = LAYER ? (bi2h[HH + c] + bh2h[HH + c]) : b0[c];
    }
    const int rr = tid >> 5, cl = tid & 31;     // reducer mapping

    for (int t = 0; t < SS; ++t) {
        if (tid == 0) {
            if (LAYER == 0) {
                if (t >= 1) wait_ge(c0 + rg, 16u * (unsigned)t);                     // h0(t-1) ready
                if (t >= RING_D) wait_ge(c1 + rg, 16u * (unsigned)(t - RING_D + 1)); // slot free
            } else {
                wait_ge(c0 + rg, 16u * (unsigned)(t + 1));                           // h0(t) ready
                if (t >= 1) wait_ge(c1 + rg, 16u * (unsigned)t);                     // h1(t-1) ready
            }
        }
        __syncthreads();

        // ---- stage h (+x) into LDS: loads first (pipelined), writes after ----
        if (LAYER == 0) {
            const float* hsrc = (t == 0)
                ? (hprev + (size_t)row0 * HH)
                : (ring + (size_t)((t - 1) & (RING_D - 1)) * BH + (size_t)row0 * HH);
            float2 tmp[8];
            #pragma unroll
            for (int u = 0; u < 8; ++u) tmp[u] = ld_coh2(hsrc + u * HH + 2 * tid);
            float4 xv[2];
            #pragma unroll
            for (int v = 0; v < 2; ++v) {
                int rx = 4 * v + (tid >> 6);
                xv[v] = *(const float4*)(x + ((size_t)(row0 + rx) * SS + t) * II + 4 * (tid & 63));
            }
            #pragma unroll
            for (int u = 0; u < 8; ++u) *(float2*)&hbuf[u * STR + 2 * tid] = tmp[u];
            #pragma unroll
            for (int v = 0; v < 2; ++v) {
                int rx = 4 * v + (tid >> 6);
                *(float4*)&hbuf[rx * STR + 512 + 4 * (tid & 63)] = xv[v];
            }
        } else {
            const float* h0src = ring + (size_t)(t & (RING_D - 1)) * BH + (size_t)row0 * HH;
            const float* h1src = (t == 0)
                ? (hprev + BH + (size_t)row0 * HH)
                : (H1 + (size_t)(t - 1) * BH + (size_t)row0 * HH);
            float2 ta[8], tb[8];
            #pragma unroll
            for (int u = 0; u < 8; ++u) ta[u] = ld_coh2(h0src + u * HH + 2 * tid);
            #pragma unroll
            for (int u = 0; u < 8; ++u) tb[u] = ld_coh2(h1src + u * HH + 2 * tid);
            #pragma unroll
            for (int u = 0; u < 8; ++u) *(float2*)&hbuf[u * STR + 2 * tid] = ta[u];
            #pragma unroll
            for (int u = 0; u < 8; ++u) *(float2*)&hbuf[u * STR + 512 + 2 * tid] = tb[u];
        }
        __syncthreads();

        // ---- FMA over this thread's k-slice (weights in regs) ----
        float4 acc[8];
        #pragma unroll
        for (int r = 0; r < 8; ++r) acc[r] = make_float4(0.f, 0.f, 0.f, 0.f);
        #pragma unroll
        for (int r = 0; r < 8; ++r) {
            #pragma unroll
            for (int j = 0; j < NJ; ++j) {
                float4 h4 = *(const float4*)&hbuf[r * STR + j * 128 + kg * 4];
                float4 wa = w4[j * 4 + 0];
                float4 wb = w4[j * 4 + 1];
                float4 wc = w4[j * 4 + 2];
                float4 wd = w4[j * 4 + 3];
                acc[r].x = fmaf(h4.x, wa.x, acc[r].x);
                acc[r].y = fmaf(h4.x, wa.y, acc[r].y);
                acc[r].z = fmaf(h4.x, wa.z, acc[r].z);
                acc[r].w = fmaf(h4.x, wa.w, acc[r].w);
                acc[r].x = fmaf(h4.y, wb.x, acc[r].x);
                acc[r].y = fmaf(h4.y, wb.y, acc[r].y);
                acc[r].z = fmaf(h4.y, wb.z, acc[r].z);
                acc[r].w = fmaf(h4.y, wb.w, acc[r].w);
                acc[r].x = fmaf(h4.z, wc.x, acc[r].x);
                acc[r].y = fmaf(h4.z, wc.y, acc[r].y);
                acc[r].z = fmaf(h4.z, wc.z, acc[r].z);
                acc[r].w = fmaf(h4.z, wc.w, acc[r].w);
                acc[r].x = fmaf(h4.w, wd.x, acc[r].x);
                acc[r].y = fmaf(h4.w, wd.y, acc[r].y);
                acc[r].z = fmaf(h4.w, wd.z, acc[r].z);
                acc[r].w = fmaf(h4.w, wd.w, acc[r].w);
            }
        }

        // ---- k-partial reduction via LDS transpose ----
        #pragma unroll
        for (int r = 0; r < 8; ++r) {
            pbuf[(r * 32 + cgrp * 4 + 0) * PSTR + kg] = acc[r].x;
            pbuf[(r * 32 + cgrp * 4 + 1) * PSTR + kg] = acc[r].y;
            pbuf[(r * 32 + cgrp * 4 + 2) * PSTR + kg] = acc[r].z;
            pbuf[(r * 32 + cgrp * 4 + 3) * PSTR + kg] = acc[r].w;
        }
        __syncthreads();
        {
            float s = 0.f;
            #pragma unroll
            for (int j2 = 0; j2 < 8; ++j2) {
                float4 v = *(const float4*)&pbuf[(rr * 32 + cl) * PSTR + 4 * j2];
                s += (v.x + v.y) + (v.z + v.w);
            }
            float o = tanhf(s + bias_red);
            float* dst = LAYER
                ? (H1 + (size_t)t * BH + (size_t)(row0 + rr) * HH + col0 + cl)
                : (ring + (size_t)(t & (RING_D - 1)) * BH + (size_t)(row0 + rr) * HH + col0 + cl);
            st_coh1(dst, o);
        }
        __syncthreads();   // drains each wave's sc1 stores (vmcnt(0)) before flag
        if (tid == 0) add_flag((LAYER ? c1 : c0) + rg);
    }
}

__global__ __launch_bounds__(256, 1) void rnn_seq6(
    const float* __restrict__ x, const float* __restrict__ hprev,
    const float* __restrict__ Wi2h, const float* __restrict__ bi2h,
    const float* __restrict__ Wh2h, const float* __restrict__ bh2h,
    const float* __restrict__ W0, const float* __restrict__ b0,
    float* __restrict__ ring, float* __restrict__ H1,
    unsigned* __restrict__ c0, unsigned* __restrict__ c1)
{
    extern __shared__ float lds[];
    float* hbuf = lds;
    float* pbuf = lds + HREG;
    if (blockIdx.x >> 7)
        rnn_body<1>(x, hprev, Wi2h, bi2h, Wh2h, bh2h, W0, b0, ring, H1, c0, c1, hbuf, pbuf);
    else
        rnn_body<0>(x, hprev, Wi2h, bi2h, Wh2h, bh2h, W0, b0, ring, H1, c0, c1, hbuf, pbuf);
}

// ---------------- out GEMM: out[b][s][:] = H1[s][b][:] @ Wout + bout ----------------
__global__ __launch_bounds__(256) void out_k(
    const float* __restrict__ H1, const float* __restrict__ Wout,
    const float* __restrict__ bout, float* __restrict__ out)
{
    __shared__ float wchunk[32 * 256];
    __shared__ float htile[16 * 32];
    const int tid = threadIdx.x;
    const int r0 = blockIdx.x * 16;

    float acc[16];
    #pragma unroll
    for (int mm = 0; mm < 16; ++mm) acc[mm] = 0.f;

    for (int kc = 0; kc < HH; kc += 32) {
        for (int idx = tid; idx < 32 * 256; idx += 256)
            wchunk[idx] = Wout[(size_t)(kc + (idx >> 8)) * OO + (idx & 255)];
        for (int idx = tid; idx < 16 * 32; idx += 256) {
            int mm = idx >> 5, kk = idx & 31;
            htile[idx] = H1[(size_t)(r0 + mm) * HH + kc + kk];
        }
        __syncthreads();
        for (int kk = 0; kk < 32; ++kk) {
            float w = wchunk[kk * 256 + tid];
            #pragma unroll
            for (int mm = 0; mm < 16; ++mm)
                acc[mm] = fmaf(htile[mm * 32 + kk], w, acc[mm]);
        }
        __syncthreads();
    }
    float bo = bout[tid];
    #pragma unroll
    for (int mm = 0; mm < 16; ++mm) {
        int rr = r0 + mm;
        int s = rr >> 6, b = rr & 63;
        out[((size_t)b * SS + s) * OO + tid] = acc[mm] + bo;
    }
}

// ---------------- final hidden states ----------------
__global__ __launch_bounds__(256) void tail_k(
    const float* __restrict__ ring, const float* __restrict__ H1,
    float* __restrict__ out_tail)
{
    int gid = blockIdx.x * 256 + threadIdx.x;
    if (gid < BB * HH)
        out_tail[gid] = ring[((SS - 1) & (RING_D - 1)) * BH + gid];
    else if (gid < 2 * BB * HH)
        out_tail[gid] = H1[(size_t)(SS - 1) * BH + (gid - BB * HH)];
}

// ---------------- launch ----------------
extern "C" void kernel_launch(void* const* d_in, const int* in_sizes, int n_in,
                              void* d_out, int out_size, void* d_ws, size_t ws_size,
                              hipStream_t stream)
{
    const float* x     = (const float*)d_in[0];
    const float* hprev = (const float*)d_in[1];
    const float* Win   = (const float*)d_in[2];
    const float* bin   = (const float*)d_in[3];
    const float* Wi2h  = (const float*)d_in[4];
    const float* bi2h  = (const float*)d_in[5];
    const float* Wh2h  = (const float*)d_in[6];
    const float* bh2h  = (const float*)d_in[7];
    const float* Wout  = (const float*)d_in[8];
    const float* bout  = (const float*)d_in[9];

    float* ws   = (float*)d_ws;
    float* W0   = ws;
    float* b0   = W0 + (size_t)II * HH;
    float* ring = b0 + HH;
    float* H1   = ring + (size_t)RING_D * BH;
    unsigned* cnt = (unsigned*)(H1 + (size_t)SS * BH);
    unsigned* c0 = cnt;
    unsigned* c1 = cnt + 8;
    float* out  = (float*)d_out;

    hipMemsetAsync(cnt, 0, 16 * sizeof(unsigned), stream);
    fold_k<<<dim3((II * HH + HH + 255) / 256), dim3(256), 0, stream>>>(
        Win, bin, Wi2h, bi2h, bh2h, W0, b0);
    hipFuncSetAttribute((const void*)rnn_seq6,
                        hipFuncAttributeMaxDynamicSharedMemorySize, LDS_BYTES);
    rnn_seq6<<<dim3(256), dim3(256), LDS_BYTES, stream>>>(
        x, hprev, Wi2h, bi2h, Wh2h, bh2h, W0, b0, ring, H1, c0, c1);
    out_k<<<dim3(BB * SS / 16), dim3(256), 0, stream>>>(H1, Wout, bout, out);
    tail_k<<<dim3((2 * BB * HH) / 256), dim3(256), 0, stream>>>(
        ring, H1, out + (size_t)BB * SS * OO);
}

// Round 8
// 5112.004 us; speedup vs baseline: 1.1883x; 1.1883x over previous
//
#include <hip/hip_runtime.h>
#include <math.h>

// CustomRNN: B=64,S=512,I=256,H=512,O=256,L=2 (fp32)
// R8 = R7 verbatim resubmit (R7 was an infra failure; kernel audited hang-free).
// R7 = R3 compute/dataflow (pin4 reverted) + ONE change class: sync overhaul.
//  Exchange readiness is DATA-EMBEDDED: each exchanged h value carries an 8-bit
//  epoch tag in its low mantissa bits ((t+1)&255; |err|<=3e-5). Consumers poll
//  their own sc1-loaded elements for the tag — producer's sc1 store IS the flag.
//  No quorum counters on the critical path. Rings: h0ring/h1ring depth 2
//  (epoch-per-slot unique => no stale reads; 0xAA poison never matches a tag).
//  Only counter left: c1 (L1 tick progress) as L0's depth-2 overwrite throttle
//  (off critical path). H1 archive now NORMAL stores (read post-kernel only).
//   fold:  W0 = Win@Wi0, b0 = bin@Wi0 + bi0 + bh0
//   rnn:   persistent 256 WGs (1/CU). L0: h0(t)=tanh(h0(t-1)@Wh0 + x_t@W0 + b0)
//          L1: h1(t)=tanh(h0(t)@Wi1 + h1(t-1)@Wh1 + b1)
//   out_k: out = H1 @ W_out + b_out ; tail_k: final hidden states.

constexpr int BB = 64;
constexpr int SS = 512;
constexpr int II = 256;
constexpr int HH = 512;
constexpr int OO = 256;
constexpr int BH = BB * HH;       // 32768
constexpr int STR0 = 772;         // L0 row stride (512 h + 256 x + pad)
constexpr int STR1 = 1028;        // L1 row stride (512 h0 + 512 h1 + pad)
constexpr int PSTR = 36;
constexpr int HREG = 8 * STR1;    // 8224 floats
constexpr int PREG = 8 * 32 * PSTR;
constexpr int LDS_BYTES = (HREG + PREG) * 4;  // 69760 B

#define SCOPE_AGENT __HIP_MEMORY_SCOPE_AGENT

__device__ __forceinline__ unsigned ld_flag(const unsigned* p) {
    return __hip_atomic_load((unsigned*)p, __ATOMIC_RELAXED, SCOPE_AGENT);
}
__device__ __forceinline__ void add_flag(unsigned* p) {
    __hip_atomic_fetch_add(p, 1u, __ATOMIC_RELAXED, SCOPE_AGENT);
}
__device__ __forceinline__ void wait_ge(const unsigned* p, unsigned target) {
    while (ld_flag(p) < target) __builtin_amdgcn_s_sleep(1);
}
__device__ __forceinline__ float ld_coh1(const float* p) {
    return __hip_atomic_load((float*)p, __ATOMIC_RELAXED, SCOPE_AGENT);
}
__device__ __forceinline__ void st_coh1(float* p, float a) {
    __hip_atomic_store(p, a, __ATOMIC_RELAXED, SCOPE_AGENT);
}
// embed 8-bit epoch tag in low mantissa bits
__device__ __forceinline__ float tagf(float v, unsigned t8) {
    return __uint_as_float((__float_as_uint(v) & 0xFFFFFF00u) | t8);
}
__device__ __forceinline__ bool tag_ok(float v, unsigned t8) {
    return (__float_as_uint(v) & 255u) == t8;
}

// ---------------- fold: W0 = Win@Wi0, b0 = bin@Wi0 + bi0 + bh0 ----------------
__global__ __launch_bounds__(256) void fold_k(
    const float* __restrict__ Win, const float* __restrict__ bin,
    const float* __restrict__ Wi2h, const float* __restrict__ bi2h,
    const float* __restrict__ bh2h,
    float* __restrict__ W0, float* __restrict__ b0)
{
    int gid = blockIdx.x * 256 + threadIdx.x;
    const float* Wi0 = Wi2h;
    if (gid < II * HH) {
        int i = gid / HH, j = gid % HH;
        float acc = 0.f;
        for (int k = 0; k < HH; ++k)
            acc = fmaf(Win[i * HH + k], Wi0[k * HH + j], acc);
        W0[gid] = acc;
    } else if (gid < II * HH + HH) {
        int j = gid - II * HH;
        float acc = bi2h[j] + bh2h[j];
        for (int k = 0; k < HH; ++k)
            acc = fmaf(bin[k], Wi0[k * HH + j], acc);
        b0[j] = acc;
    }
}

// ---------------- persistent sequential kernel ----------------
template <int LAYER>
__device__ __forceinline__ void rnn_body(
    const float* __restrict__ x, const float* __restrict__ hprev,
    const float* __restrict__ Wi2h, const float* __restrict__ bi2h,
    const float* __restrict__ Wh2h, const float* __restrict__ bh2h,
    const float* __restrict__ W0, const float* __restrict__ b0,
    float* __restrict__ h0ring, float* __restrict__ h1ring,
    float* __restrict__ H1, unsigned* __restrict__ c1,
    float* hbuf, float* pbuf)
{
    constexpr int NJ  = LAYER ? 8 : 6;           // k-range = NJ*128
    constexpr int STR = LAYER ? STR1 : STR0;

    const int tid  = threadIdx.x;
    const int id   = blockIdx.x & 127;
    const int rg   = id >> 4;        // 0..7  (8 rows each)
    const int cg   = id & 15;        // 0..15 (32 cols each)
    const int row0 = rg * 8;
    const int col0 = cg * 32;
    const int kg   = tid & 31;
    const int cgrp = (tid >> 5) & 7;
    const int cbase = col0 + cgrp * 4;

    float bias_red;
    {
        int c = col0 + (tid & 31);
        bias_red = LAYER ? (bi2h[HH + c] + bh2h[HH + c]) : b0[c];
    }
    const int rr = tid >> 5, cl = tid & 31;     // reducer mapping

    for (int t = 0; t < SS; ++t) {
        // L0 overwrite throttle (depth-2 ring): L1 must have finished t-2.
        if (LAYER == 0 && t >= 2 && tid == 0)
            wait_ge(c1 + rg, 16u * (unsigned)(t - 1));
        __syncthreads();

        // ---- stage h (+x) into LDS ----
        if (LAYER == 0) {
            if (t == 0) {
                float2 tmp[8];
                #pragma unroll
                for (int u = 0; u < 8; ++u)
                    tmp[u] = *(const float2*)(hprev + (size_t)(row0 + u) * HH + 2 * tid);
                #pragma unroll
                for (int u = 0; u < 8; ++u)
                    *(float2*)&hbuf[u * STR + 2 * tid] = tmp[u];
            } else {
                const float* rs = h0ring + (size_t)((t - 1) & 1) * BH + (size_t)row0 * HH;
                const unsigned tg = (unsigned)(t & 255);   // epoch of h0(t-1)
                float v[16];
                for (;;) {
                    bool ok = true;
                    #pragma unroll
                    for (int u = 0; u < 8; ++u) {
                        v[2 * u + 0] = ld_coh1(rs + u * HH + tid);
                        v[2 * u + 1] = ld_coh1(rs + u * HH + 256 + tid);
                    }
                    #pragma unroll
                    for (int e = 0; e < 16; ++e) ok &= tag_ok(v[e], tg);
                    if (ok) break;
                    __builtin_amdgcn_s_sleep(1);
                }
                #pragma unroll
                for (int u = 0; u < 8; ++u) {
                    hbuf[u * STR + tid]       = v[2 * u + 0];
                    hbuf[u * STR + 256 + tid] = v[2 * u + 1];
                }
            }
            float4 xv[2];
            #pragma unroll
            for (int w = 0; w < 2; ++w) {
                int rx = 4 * w + (tid >> 6);
                xv[w] = *(const float4*)(x + ((size_t)(row0 + rx) * SS + t) * II + 4 * (tid & 63));
            }
            #pragma unroll
            for (int w = 0; w < 2; ++w) {
                int rx = 4 * w + (tid >> 6);
                *(float4*)&hbuf[rx * STR + 512 + 4 * (tid & 63)] = xv[w];
            }
        } else {
            // h1(t-1): the critical recurrence — poll it first
            if (t == 0) {
                float2 tmp[8];
                #pragma unroll
                for (int u = 0; u < 8; ++u)
                    tmp[u] = *(const float2*)(hprev + BH + (size_t)(row0 + u) * HH + 2 * tid);
                #pragma unroll
                for (int u = 0; u < 8; ++u)
                    *(float2*)&hbuf[u * STR + 512 + 2 * tid] = tmp[u];
            } else {
                const float* rs = h1ring + (size_t)((t - 1) & 1) * BH + (size_t)row0 * HH;
                const unsigned tg = (unsigned)(t & 255);   // epoch of h1(t-1)
                float v[16];
                for (;;) {
                    bool ok = true;
                    #pragma unroll
                    for (int u = 0; u < 8; ++u) {
                        v[2 * u + 0] = ld_coh1(rs + u * HH + tid);
                        v[2 * u + 1] = ld_coh1(rs + u * HH + 256 + tid);
                    }
                    #pragma unroll
                    for (int e = 0; e < 16; ++e) ok &= tag_ok(v[e], tg);
                    if (ok) break;
                    __builtin_amdgcn_s_sleep(1);
                }
                #pragma unroll
                for (int u = 0; u < 8; ++u) {
                    hbuf[u * STR + 512 + tid]       = v[2 * u + 0];
                    hbuf[u * STR + 512 + 256 + tid] = v[2 * u + 1];
                }
            }
            {   // h0(t): usually already posted (L0 runs ahead)
                const float* rs = h0ring + (size_t)(t & 1) * BH + (size_t)row0 * HH;
                const unsigned tg = (unsigned)((t + 1) & 255);   // epoch of h0(t)
                float v[16];
                for (;;) {
                    bool ok = true;
                    #pragma unroll
                    for (int u = 0; u < 8; ++u) {
                        v[2 * u + 0] = ld_coh1(rs + u * HH + tid);
                        v[2 * u + 1] = ld_coh1(rs + u * HH + 256 + tid);
                    }
                    #pragma unroll
                    for (int e = 0; e < 16; ++e) ok &= tag_ok(v[e], tg);
                    if (ok) break;
                    __builtin_amdgcn_s_sleep(1);
                }
                #pragma unroll
                for (int u = 0; u < 8; ++u) {
                    hbuf[u * STR + tid]       = v[2 * u + 0];
                    hbuf[u * STR + 256 + tid] = v[2 * u + 1];
                }
            }
        }
        __syncthreads();

        // ---- FMA over this thread's k-slice (weights remat from L2) ----
        float4 acc[8];
        #pragma unroll
        for (int r = 0; r < 8; ++r) acc[r] = make_float4(0.f, 0.f, 0.f, 0.f);
        #pragma unroll
        for (int r = 0; r < 8; ++r) {
            #pragma unroll
            for (int j = 0; j < NJ; ++j) {
                int k = j * 128 + kg * 4;
                const float* wsrc;
                if (LAYER == 0)
                    wsrc = (k < 512) ? (Wh2h + (size_t)k * HH + cbase)
                                     : (W0 + (size_t)(k - 512) * HH + cbase);
                else
                    wsrc = (k < 512) ? (Wi2h + (size_t)HH * HH + (size_t)k * HH + cbase)
                                     : (Wh2h + (size_t)HH * HH + (size_t)(k - 512) * HH + cbase);
                float4 h4 = *(const float4*)&hbuf[r * STR + k];
                float4 wa = *(const float4*)(wsrc);
                float4 wb = *(const float4*)(wsrc + HH);
                float4 wc = *(const float4*)(wsrc + 2 * HH);
                float4 wd = *(const float4*)(wsrc + 3 * HH);
                acc[r].x = fmaf(h4.x, wa.x, acc[r].x);
                acc[r].y = fmaf(h4.x, wa.y, acc[r].y);
                acc[r].z = fmaf(h4.x, wa.z, acc[r].z);
                acc[r].w = fmaf(h4.x, wa.w, acc[r].w);
                acc[r].x = fmaf(h4.y, wb.x, acc[r].x);
                acc[r].y = fmaf(h4.y, wb.y, acc[r].y);
                acc[r].z = fmaf(h4.y, wb.z, acc[r].z);
                acc[r].w = fmaf(h4.y, wb.w, acc[r].w);
                acc[r].x = fmaf(h4.z, wc.x, acc[r].x);
                acc[r].y = fmaf(h4.z, wc.y, acc[r].y);
                acc[r].z = fmaf(h4.z, wc.z, acc[r].z);
                acc[r].w = fmaf(h4.z, wc.w, acc[r].w);
                acc[r].x = fmaf(h4.w, wd.x, acc[r].x);
                acc[r].y = fmaf(h4.w, wd.y, acc[r].y);
                acc[r].z = fmaf(h4.w, wd.z, acc[r].z);
                acc[r].w = fmaf(h4.w, wd.w, acc[r].w);
            }
        }

        // ---- k-partial reduction via LDS transpose ----
        #pragma unroll
        for (int r = 0; r < 8; ++r) {
            pbuf[(r * 32 + cgrp * 4 + 0) * PSTR + kg] = acc[r].x;
            pbuf[(r * 32 + cgrp * 4 + 1) * PSTR + kg] = acc[r].y;
            pbuf[(r * 32 + cgrp * 4 + 2) * PSTR + kg] = acc[r].z;
            pbuf[(r * 32 + cgrp * 4 + 3) * PSTR + kg] = acc[r].w;
        }
        __syncthreads();
        {
            float s = 0.f;
            #pragma unroll
            for (int j2 = 0; j2 < 8; ++j2) {
                float4 v = *(const float4*)&pbuf[(rr * 32 + cl) * PSTR + 4 * j2];
                s += (v.x + v.y) + (v.z + v.w);
            }
            float o = tanhf(s + bias_red);
            const unsigned myt8 = (unsigned)((t + 1) & 255);
            if (LAYER == 0) {
                st_coh1(h0ring + (size_t)(t & 1) * BH + (size_t)(row0 + rr) * HH + col0 + cl,
                        tagf(o, myt8));
            } else {
                st_coh1(h1ring + (size_t)(t & 1) * BH + (size_t)(row0 + rr) * HH + col0 + cl,
                        tagf(o, myt8));
                H1[(size_t)t * BH + (size_t)(row0 + rr) * HH + col0 + cl] = o;  // archive (normal)
            }
        }
        __syncthreads();
        if (LAYER == 1 && tid == 0) add_flag(c1 + rg);
    }
}

__global__ __launch_bounds__(256, 1) void rnn_seq7(
    const float* __restrict__ x, const float* __restrict__ hprev,
    const float* __restrict__ Wi2h, const float* __restrict__ bi2h,
    const float* __restrict__ Wh2h, const float* __restrict__ bh2h,
    const float* __restrict__ W0, const float* __restrict__ b0,
    float* __restrict__ h0ring, float* __restrict__ h1ring,
    float* __restrict__ H1, unsigned* __restrict__ c1)
{
    extern __shared__ float lds[];
    float* hbuf = lds;
    float* pbuf = lds + HREG;
    if (blockIdx.x >> 7)
        rnn_body<1>(x, hprev, Wi2h, bi2h, Wh2h, bh2h, W0, b0,
                    h0ring, h1ring, H1, c1, hbuf, pbuf);
    else
        rnn_body<0>(x, hprev, Wi2h, bi2h, Wh2h, bh2h, W0, b0,
                    h0ring, h1ring, H1, c1, hbuf, pbuf);
}

// ---------------- out GEMM: out[b][s][:] = H1[s][b][:] @ Wout + bout ----------------
__global__ __launch_bounds__(256) void out_k(
    const float* __restrict__ H1, const float* __restrict__ Wout,
    const float* __restrict__ bout, float* __restrict__ out)
{
    __shared__ float wchunk[32 * 256];
    __shared__ float htile[16 * 32];
    const int tid = threadIdx.x;
    const int r0 = blockIdx.x * 16;

    float acc[16];
    #pragma unroll
    for (int mm = 0; mm < 16; ++mm) acc[mm] = 0.f;

    for (int kc = 0; kc < HH; kc += 32) {
        for (int idx = tid; idx < 32 * 256; idx += 256)
            wchunk[idx] = Wout[(size_t)(kc + (idx >> 8)) * OO + (idx & 255)];
        for (int idx = tid; idx < 16 * 32; idx += 256) {
            int mm = idx >> 5, kk = idx & 31;
            htile[idx] = H1[(size_t)(r0 + mm) * HH + kc + kk];
        }
        __syncthreads();
        for (int kk = 0; kk < 32; ++kk) {
            float w = wchunk[kk * 256 + tid];
            #pragma unroll
            for (int mm = 0; mm < 16; ++mm)
                acc[mm] = fmaf(htile[mm * 32 + kk], w, acc[mm]);
        }
        __syncthreads();
    }
    float bo = bout[tid];
    #pragma unroll
    for (int mm = 0; mm < 16; ++mm) {
        int rr = r0 + mm;
        int s = rr >> 6, b = rr & 63;
        out[((size_t)b * SS + s) * OO + tid] = acc[mm] + bo;
    }
}

// ---------------- final hidden states ----------------
__global__ __launch_bounds__(256) void tail_k(
    const float* __restrict__ h0ring, const float* __restrict__ H1,
    float* __restrict__ out_tail)
{
    int gid = blockIdx.x * 256 + threadIdx.x;
    if (gid < BB * HH)
        out_tail[gid] = h0ring[(size_t)((SS - 1) & 1) * BH + gid];  // tagged (err<=3e-5)
    else if (gid < 2 * BB * HH)
        out_tail[gid] = H1[(size_t)(SS - 1) * BH + (gid - BB * HH)];
}

// ---------------- launch ----------------
extern "C" void kernel_launch(void* const* d_in, const int* in_sizes, int n_in,
                              void* d_out, int out_size, void* d_ws, size_t ws_size,
                              hipStream_t stream)
{
    const float* x     = (const float*)d_in[0];
    const float* hprev = (const float*)d_in[1];
    const float* Win   = (const float*)d_in[2];
    const float* bin   = (const float*)d_in[3];
    const float* Wi2h  = (const float*)d_in[4];
    const float* bi2h  = (const float*)d_in[5];
    const float* Wh2h  = (const float*)d_in[6];
    const float* bh2h  = (const float*)d_in[7];
    const float* Wout  = (const float*)d_in[8];
    const float* bout  = (const float*)d_in[9];

    float* ws     = (float*)d_ws;
    float* W0     = ws;
    float* b0     = W0 + (size_t)II * HH;
    float* h0ring = b0 + HH;                       // 2*BH floats
    float* h1ring = h0ring + 2 * (size_t)BH;       // 2*BH floats
    float* H1     = h1ring + 2 * (size_t)BH;       // SS*BH floats
    unsigned* c1  = (unsigned*)(H1 + (size_t)SS * BH);
    float* out    = (float*)d_out;

    hipMemsetAsync(c1, 0, 16 * sizeof(unsigned), stream);
    fold_k<<<dim3((II * HH + HH + 255) / 256), dim3(256), 0, stream>>>(
        Win, bin, Wi2h, bi2h, bh2h, W0, b0);
    hipFuncSetAttribute((const void*)rnn_seq7,
                        hipFuncAttributeMaxDynamicSharedMemorySize, LDS_BYTES);
    rnn_seq7<<<dim3(256), dim3(256), LDS_BYTES, stream>>>(
        x, hprev, Wi2h, bi2h, Wh2h, bh2h, W0, b0, h0ring, h1ring, H1, c1);
    out_k<<<dim3(BB * SS / 16), dim3(256), 0, stream>>>(H1, Wout, bout, out);
    tail_k<<<dim3((2 * BB * HH) / 256), dim3(256), 0, stream>>>(
        h0ring, H1, out + (size_t)BB * SS * OO);
}